// Round 3
// baseline (184.632 us; speedup 1.0000x reference)
//
#include <hip/hip_runtime.h>
#include <math.h>

#define B 8
#define C 64
#define HIN 224
#define WIN 224
#define PLANE (HIN*WIN)        // 50176
#define PLANE4 (PLANE/4)       // 12544
#define QUART (PLANE4/4)       // 3136
#define OH 64
#define OW 128
#define OUT_PER_BC (OH*OW)     // 8192
#define POOLED_SIZE (B*C*OH*OW) // 4194304

// ws layout (floats): [0,2048) partial sums [bc][quarter]
#define WS_PARTIAL 0

#define PI_F 3.14159265358979323846f

__device__ __forceinline__ float bilinear(const float* __restrict__ p,
                                          float ix, float iy) {
    float x0f = floorf(ix), y0f = floorf(iy);
    int x0 = (int)x0f, y0 = (int)y0f;
    float wx = ix - x0f, wy = iy - y0f;
    int x1 = min(x0 + 1, WIN - 1);
    int y1 = min(y0 + 1, HIN - 1);
    const float* r0 = p + y0 * WIN;
    const float* r1 = p + y1 * WIN;
    float v00 = r0[x0], v01 = r0[x1], v10 = r1[x0], v11 = r1[x1];
    float v0 = v00 + (v01 - v00) * wx;
    float v1 = v10 + (v11 - v10) * wx;
    return v0 + (v1 - v0) * wy;
}

// -------- K1: GAP partial sums + constant-region fill (fused) --------
// grid = bc*4 + q  (2048 blocks)
__global__ __launch_bounds__(256) void k1_gap_fill(const float* __restrict__ x,
                                                   const float* __restrict__ l_t,
                                                   float* __restrict__ ws,
                                                   float* __restrict__ out) {
    int blk = blockIdx.x;
    int bc  = blk >> 2, q = blk & 3;
    const float* plane = x + (size_t)bc * PLANE;
    const float4* p = (const float4*)plane + q * QUART;
    int tid = threadIdx.x;
    float s = 0.f;
#pragma unroll
    for (int k = 0; k < 12; ++k) {
        float4 v = p[tid + k * 256];
        s += (v.x + v.y) + (v.z + v.w);
    }
    if (tid < QUART - 12 * 256) {
        float4 v = p[tid + 12 * 256];
        s += (v.x + v.y) + (v.z + v.w);
    }

    // Constant region: grid == (0,0)+l_t outside the 64x128 corner -> after
    // 4x4 pooling every output with h>=16 || w>=32 equals ONE bilinear sample.
    {
        int b = bc >> 6;
        float gx = l_t[2 * b], gy = l_t[2 * b + 1];
        float ixc = fminf(fmaxf(((gx + 1.f) * (float)WIN - 1.f) * 0.5f, 0.f), (float)(WIN - 1));
        float iyc = fminf(fmaxf(((gy + 1.f) * (float)HIN - 1.f) * 0.5f, 0.f), (float)(HIN - 1));
        float vc = bilinear(plane, ixc, iyc);
        float4 v4 = make_float4(vc, vc, vc, vc);
        float4* o4 = (float4*)(out + (size_t)bc * OUT_PER_BC);
        int end = q * 480 + 480;
        for (int it = q * 480 + tid; it < end; it += 256) {
            int off;
            if (it < 384) {                 // rows 0..15, cols 32..127 (24 float4/row)
                int r = it / 24;
                off = r * 32 + 8 + (it - r * 24);
            } else {                        // rows 16..63, full rows (32 float4/row)
                int t2 = it - 384;
                off = (16 + (t2 >> 5)) * 32 + (t2 & 31);
            }
            o4[off] = v4;
        }
    }

    for (int off = 32; off; off >>= 1) s += __shfl_down(s, off, 64);
    __shared__ float lds[4];
    if ((tid & 63) == 0) lds[tid >> 6] = s;
    __syncthreads();
    if (tid == 0) ws[WS_PARTIAL + blk] = lds[0] + lds[1] + lds[2] + lds[3];
}

// -------- K2: fused MLP + coords(LDS) + corner sampling --------
// 1024 blocks x 256 threads. Block -> bc = blockIdx>>1 (one of 512 planes),
// h0 = (blockIdx&1)*8 (covers pooled rows h0..h0+7, all 32 corner cols).
__global__ __launch_bounds__(256) void k2_fused(const float* __restrict__ x,
                                                const float* __restrict__ w1,
                                                const float* __restrict__ b1,
                                                const float* __restrict__ w2,
                                                const float* __restrict__ b2,
                                                const float* __restrict__ l_t,
                                                const float* __restrict__ ws,
                                                float* __restrict__ out,
                                                float* __restrict__ out_weight) {
    __shared__ float2 scoords[4096];   // 32 KB: layout s = gr*128 + dj*32 + w
    __shared__ float branch[B * C];    // 512
    __shared__ float hidden[256];      // 8 x 32
    __shared__ float wv[16];
    int tid = threadIdx.x;
    int bc = blockIdx.x >> 1;
    int b  = bc >> 6;
    int h0 = (blockIdx.x & 1) * 8;

    // --- stage 1: branch = GAP result from k1 partials ---
    for (int i = tid; i < B * C; i += 256) {
        const float* pp = ws + WS_PARTIAL + i * 4;
        branch[i] = (pp[0] + pp[1] + pp[2] + pp[3]) * (1.0f / PLANE);
    }
    __syncthreads();
    // --- stage 2: tiny MLP -> wv[16] ---
    {
        int bb = tid >> 5, m = tid & 31;
        float h = b1[m];
#pragma unroll 8
        for (int c = 0; c < C; ++c) h += branch[bb * C + c] * w1[c * 32 + m];
        hidden[tid] = fmaxf(h, 0.f);
    }
    __syncthreads();
    if (tid < 16) {
        int bb = tid >> 1, k = tid & 1;
        float s = b2[k];
#pragma unroll
        for (int m = 0; m < 32; ++m) s += hidden[bb * 32 + m] * w2[m * 2 + k];
        float v = 1.f / (1.f + expf(-s));
        wv[tid] = v;
        if (blockIdx.x == 0) out_weight[tid] = v;
    }
    __syncthreads();

    // --- stage 3: this block's 4096 sampling coords into LDS ---
    float lo = logf(wv[b * 2 + 0] * 0.01f);
    float hi = logf(wv[b * 2 + 1] * 0.6f);
    float ltx = l_t[b * 2 + 0], lty = l_t[b * 2 + 1];
#pragma unroll
    for (int k = 0; k < 16; ++k) {
        int s = tid + k * 256;          // 0..4095
        int gr = s >> 7;                // 0..31  (grid row - 4*h0)
        int dj = (s >> 5) & 3;
        int w  = s & 31;
        int i = h0 * 4 + gr;            // grid row 0..63
        int j = w * 4 + dj;             // grid col 0..127
        float xg = (float)(i - 32) * (1.f / 32.f);
        float yg = (float)(j - 64) * (1.f / 64.f);
        float rr = sqrtf(xg * xg + yg * yg);
        float logr = logf(fmaxf(rr, 1e-12f));
        float r = 64.f * (logr - lo) / (hi - lo);
        float a = atan2f(yg, xg);
        if (!(a > 0.f)) a = 2.f * PI_F + a;
        float t = 0.5f * a * 64.f / PI_F;
        float gx = t * (1.f / 32.f) - 1.f + ltx;
        float gy = r * (1.f / 32.f) - 1.f + lty;
        float ix = ((gx + 1.f) * (float)WIN - 1.f) * 0.5f;
        float iy = ((gy + 1.f) * (float)HIN - 1.f) * 0.5f;
        ix = fminf(fmaxf(ix, 0.f), (float)(WIN - 1));
        iy = fminf(fmaxf(iy, 0.f), (float)(HIN - 1));
        scoords[s] = make_float2(ix, iy);
    }
    __syncthreads();

    // --- stage 4: 16-sample bilinear pooling for 256 outputs ---
    const float* plane = x + (size_t)bc * PLANE;
    int hr = tid >> 5;                  // 0..7 (pooled row - h0)
    int w  = tid & 31;                  // pooled col 0..31
    float acc = 0.f;
#pragma unroll
    for (int di = 0; di < 4; ++di) {
#pragma unroll
        for (int dj = 0; dj < 4; ++dj) {
            float2 cxy = scoords[(hr * 4 + di) * 128 + dj * 32 + w];
            acc += bilinear(plane, cxy.x, cxy.y);
        }
    }
    out[((size_t)bc << 13) + ((h0 + hr) << 7) + w] = acc * (1.f / 16.f);
}

extern "C" void kernel_launch(void* const* d_in, const int* in_sizes, int n_in,
                              void* d_out, int out_size, void* d_ws, size_t ws_size,
                              hipStream_t stream) {
    const float* x   = (const float*)d_in[0];
    const float* l_t = (const float*)d_in[1];
    const float* w1  = (const float*)d_in[2];
    const float* b1  = (const float*)d_in[3];
    const float* w2  = (const float*)d_in[4];
    const float* b2  = (const float*)d_in[5];
    float* out = (float*)d_out;
    float* ws  = (float*)d_ws;

    k1_gap_fill<<<dim3(B * C * 4), dim3(256), 0, stream>>>(x, l_t, ws, out);
    k2_fused<<<dim3(1024), dim3(256), 0, stream>>>(x, w1, b1, w2, b2, l_t, ws,
                                                   out, out + POOLED_SIZE);
}

// Round 4
// 181.934 us; speedup vs baseline: 1.0148x; 1.0148x over previous
//
#include <hip/hip_runtime.h>
#include <math.h>

#define B 8
#define C 64
#define HIN 224
#define WIN 224
#define PLANE (HIN*WIN)        // 50176
#define PLANE4 (PLANE/4)       // 12544
#define QUART (PLANE4/4)       // 3136
#define OH 64
#define OW 128
#define OUT_PER_BC (OH*OW)     // 8192
#define POOLED_SIZE (B*C*OH*OW) // 4194304

// ws layout (floats):
// [0, 2048)            : partial sums [bc][quarter]
// [4096, 4096+262144)  : descriptors [b][8192] float4 (off00:int, dpack:int, wx, wy)
#define WS_PARTIAL 0
#define WS_DESC 4096

#define PI_F 3.14159265358979323846f

__device__ __forceinline__ float bilinear(const float* __restrict__ p,
                                          float ix, float iy) {
    float x0f = floorf(ix), y0f = floorf(iy);
    int x0 = (int)x0f, y0 = (int)y0f;
    float wx = ix - x0f, wy = iy - y0f;
    int x1 = min(x0 + 1, WIN - 1);
    int y1 = min(y0 + 1, HIN - 1);
    const float* r0 = p + y0 * WIN;
    const float* r1 = p + y1 * WIN;
    float v00 = r0[x0], v01 = r0[x1], v10 = r1[x0], v11 = r1[x1];
    float v0 = v00 + (v01 - v00) * wx;
    float v1 = v10 + (v11 - v10) * wx;
    return v0 + (v1 - v0) * wy;
}

// -------- K1: GAP partial sums + constant-region fill (fused) --------
// grid = bc*4 + q  (2048 blocks)
__global__ __launch_bounds__(256) void k1_gap_fill(const float* __restrict__ x,
                                                   const float* __restrict__ l_t,
                                                   float* __restrict__ ws,
                                                   float* __restrict__ out) {
    int blk = blockIdx.x;
    int bc  = blk >> 2, q = blk & 3;
    const float* plane = x + (size_t)bc * PLANE;
    const float4* p = (const float4*)plane + q * QUART;
    int tid = threadIdx.x;
    float s = 0.f;
#pragma unroll
    for (int k = 0; k < 12; ++k) {
        float4 v = p[tid + k * 256];
        s += (v.x + v.y) + (v.z + v.w);
    }
    if (tid < QUART - 12 * 256) {
        float4 v = p[tid + 12 * 256];
        s += (v.x + v.y) + (v.z + v.w);
    }

    // Constant region: grid == (0,0)+l_t outside the 64x128 corner -> after
    // 4x4 pooling every output with h>=16 || w>=32 equals ONE bilinear sample.
    {
        int b = bc >> 6;
        float gx = l_t[2 * b], gy = l_t[2 * b + 1];
        float ixc = fminf(fmaxf(((gx + 1.f) * (float)WIN - 1.f) * 0.5f, 0.f), (float)(WIN - 1));
        float iyc = fminf(fmaxf(((gy + 1.f) * (float)HIN - 1.f) * 0.5f, 0.f), (float)(HIN - 1));
        float vc = bilinear(plane, ixc, iyc);
        float4 v4 = make_float4(vc, vc, vc, vc);
        float4* o4 = (float4*)(out + (size_t)bc * OUT_PER_BC);
        int end = q * 480 + 480;
        for (int it = q * 480 + tid; it < end; it += 256) {
            int off;
            if (it < 384) {                 // rows 0..15, cols 32..127 (24 float4/row)
                int r = it / 24;
                off = r * 32 + 8 + (it - r * 24);
            } else {                        // rows 16..63, full rows (32 float4/row)
                int t2 = it - 384;
                off = (16 + (t2 >> 5)) * 32 + (t2 & 31);
            }
            o4[off] = v4;
        }
    }

    for (int off = 32; off; off >>= 1) s += __shfl_down(s, off, 64);
    __shared__ float lds[4];
    if ((tid & 63) == 0) lds[tid >> 6] = s;
    __syncthreads();
    if (tid == 0) ws[WS_PARTIAL + blk] = lds[0] + lds[1] + lds[2] + lds[3];
}

// -------- K2: MLP + unique bilinear descriptors (computed ONCE each) --------
// 256 blocks x 256 threads; thread p -> grid point p of batch p>>13.
__global__ __launch_bounds__(256) void k2_desc(const float* __restrict__ w1,
                                               const float* __restrict__ b1,
                                               const float* __restrict__ w2,
                                               const float* __restrict__ b2,
                                               const float* __restrict__ l_t,
                                               float* __restrict__ ws,
                                               float* __restrict__ out_weight) {
    __shared__ float branch[B * C];    // 512
    __shared__ float hidden[256];      // 8 x 32
    __shared__ float wv[16];
    int tid = threadIdx.x;
    for (int i = tid; i < B * C; i += 256) {
        const float* pp = ws + WS_PARTIAL + i * 4;
        branch[i] = (pp[0] + pp[1] + pp[2] + pp[3]) * (1.0f / PLANE);
    }
    __syncthreads();
    {
        int bb = tid >> 5, m = tid & 31;
        float h = b1[m];
#pragma unroll 8
        for (int c = 0; c < C; ++c) h += branch[bb * C + c] * w1[c * 32 + m];
        hidden[tid] = fmaxf(h, 0.f);
    }
    __syncthreads();
    if (tid < 16) {
        int bb = tid >> 1, k = tid & 1;
        float s = b2[k];
#pragma unroll
        for (int m = 0; m < 32; ++m) s += hidden[bb * 32 + m] * w2[m * 2 + k];
        float v = 1.f / (1.f + expf(-s));
        wv[tid] = v;
        if (blockIdx.x == 0) out_weight[tid] = v;
    }
    __syncthreads();

    int p = blockIdx.x * 256 + tid;    // [0, 65536)
    int b = p >> 13;
    int rem = p & 8191;
    int i = rem >> 7;                  // grid row 0..63
    int j = rem & 127;                 // grid col 0..127
    float lo = logf(wv[b * 2 + 0] * 0.01f);
    float hi = logf(wv[b * 2 + 1] * 0.6f);
    float xg = (float)(i - 32) * (1.f / 32.f);
    float yg = (float)(j - 64) * (1.f / 64.f);
    float rr = sqrtf(xg * xg + yg * yg);
    float logr = logf(fmaxf(rr, 1e-12f));
    float r = 64.f * (logr - lo) / (hi - lo);
    float a = atan2f(yg, xg);
    if (!(a > 0.f)) a = 2.f * PI_F + a;
    float t = 0.5f * a * 64.f / PI_F;
    float gx = t * (1.f / 32.f) - 1.f + l_t[b * 2 + 0];
    float gy = r * (1.f / 32.f) - 1.f + l_t[b * 2 + 1];
    float ix = ((gx + 1.f) * (float)WIN - 1.f) * 0.5f;
    float iy = ((gy + 1.f) * (float)HIN - 1.f) * 0.5f;
    ix = fminf(fmaxf(ix, 0.f), (float)(WIN - 1));
    iy = fminf(fmaxf(iy, 0.f), (float)(HIN - 1));
    // precompute bilinear descriptor
    float x0f = floorf(ix), y0f = floorf(iy);
    int x0 = (int)x0f, y0 = (int)y0f;
    float wx = ix - x0f, wy = iy - y0f;
    int dx = (x0 + 1 <= WIN - 1) ? 1 : 0;
    int dy = (y0 + 1 <= HIN - 1) ? WIN : 0;
    int off00 = y0 * WIN + x0;
    int dpack = dx | (dy << 16);
    float4 d;
    d.x = __int_as_float(off00);
    d.y = __int_as_float(dpack);
    d.z = wx;
    d.w = wy;
    ((float4*)(ws + WS_DESC))[p] = d;
}

// -------- K3: corner sampling via descriptors, one thread per output --------
// 262144 outputs -> 1024 blocks x 256 threads
__global__ __launch_bounds__(256) void k3_corner(const float* __restrict__ x,
                                                 const float4* __restrict__ desc,
                                                 float* __restrict__ out) {
    int o = blockIdx.x * 256 + threadIdx.x;   // [0, 262144)
    int b = o >> 15;
    int c = (o >> 9) & 63;
    int h = (o >> 5) & 15;
    int w = o & 31;
    const float* plane = x + (size_t)((b << 6) | c) * PLANE;
    const float4* db = desc + ((size_t)b << 13);
    float acc = 0.f;
#pragma unroll
    for (int di = 0; di < 4; ++di) {
        const float4* dr = db + ((4 * h + di) << 7) + (w << 2);
#pragma unroll
        for (int dj = 0; dj < 4; ++dj) {
            float4 d = dr[dj];
            int off00 = __float_as_int(d.x);
            int dpack = __float_as_int(d.y);
            int dx = dpack & 0xffff;
            int dy = dpack >> 16;
            float wx = d.z, wy = d.w;
            float v00 = plane[off00];
            float v01 = plane[off00 + dx];
            float v10 = plane[off00 + dy];
            float v11 = plane[off00 + dy + dx];
            float v0 = v00 + (v01 - v00) * wx;
            float v1 = v10 + (v11 - v10) * wx;
            acc += v0 + (v1 - v0) * wy;
        }
    }
    out[((size_t)((b << 6) | c) << 13) + (h << 7) + w] = acc * (1.f / 16.f);
}

extern "C" void kernel_launch(void* const* d_in, const int* in_sizes, int n_in,
                              void* d_out, int out_size, void* d_ws, size_t ws_size,
                              hipStream_t stream) {
    const float* x   = (const float*)d_in[0];
    const float* l_t = (const float*)d_in[1];
    const float* w1  = (const float*)d_in[2];
    const float* b1  = (const float*)d_in[3];
    const float* w2  = (const float*)d_in[4];
    const float* b2  = (const float*)d_in[5];
    float* out = (float*)d_out;
    float* ws  = (float*)d_ws;

    k1_gap_fill<<<dim3(B * C * 4), dim3(256), 0, stream>>>(x, l_t, ws, out);
    k2_desc<<<dim3(256), dim3(256), 0, stream>>>(w1, b1, w2, b2, l_t, ws,
                                                 out + POOLED_SIZE);
    k3_corner<<<dim3(1024), dim3(256), 0, stream>>>(x, (const float4*)(ws + WS_DESC), out);
}